// Round 16
// baseline (75.004 us; speedup 1.0000x reference)
//
#include <hip/hip_runtime.h>

// Problem dims (fixed by reference)
#define BB   2
#define NBB  32
#define PP   128
#define FF   32
#define HH   32
#define NO   8
#define OUTC 32
#define NROWS (BB*NBB*PP)   // 8192

typedef float    f32x4 __attribute__((ext_vector_type(4)));
typedef _Float16 f16x8 __attribute__((ext_vector_type(8)));
typedef _Float16 f16x4 __attribute__((ext_vector_type(4)));
typedef _Float16 f16x2 __attribute__((ext_vector_type(2)));

__device__ __forceinline__ float elu_f(float x){
    return x > 0.0f ? x : (__expf(x) - 1.0f);
}
// packed fp32x2 -> fp16x2 (RTZ), bit-cast to _Float16 vector type
__device__ __forceinline__ f16x2 pk16(float a, float b){
    return __builtin_bit_cast(f16x2, __builtin_amdgcn_cvt_pkrtz(a, b));
}

// Kernel A: node MLP + projection to pa/pb (pair_b0 folded into pa).
__global__ __launch_bounds__(256) void node_kernel(
    const float* __restrict__ x,  const float* __restrict__ msk,
    const float* __restrict__ w0, const float* __restrict__ b0,
    const float* __restrict__ w1, const float* __restrict__ b1,
    const float* __restrict__ w2, const float* __restrict__ b2,
    const float* __restrict__ pw0,const float* __restrict__ pb0,
    float* __restrict__ pa, float* __restrict__ pb)
{
    int row = blockIdx.x*256 + threadIdx.x;
    if (row >= NROWS) return;

    float xr[FF];
    const float4* xp = reinterpret_cast<const float4*>(x + (size_t)row*FF);
#pragma unroll
    for (int q=0;q<FF/4;q++){ float4 v=xp[q]; xr[4*q]=v.x; xr[4*q+1]=v.y; xr[4*q+2]=v.z; xr[4*q+3]=v.w; }

    float h[HH];
#pragma unroll
    for (int k=0;k<HH;k++) h[k]=b0[k];
#pragma unroll
    for (int m=0;m<FF;m++){
        float xm = xr[m];
#pragma unroll
        for (int k=0;k<HH;k++) h[k] += xm * w0[m*HH+k];
    }
#pragma unroll
    for (int k=0;k<HH;k++) h[k]=elu_f(h[k]);

    float g[HH];
#pragma unroll
    for (int k=0;k<HH;k++) g[k]=b1[k];
#pragma unroll
    for (int m=0;m<HH;m++){
        float hm=h[m];
#pragma unroll
        for (int k=0;k<HH;k++) g[k] += hm * w1[m*HH+k];
    }
#pragma unroll
    for (int k=0;k<HH;k++) g[k]=elu_f(g[k]);

    float mk = msk[row];
    float npj[NO];
#pragma unroll
    for (int k=0;k<NO;k++) npj[k]=b2[k];
#pragma unroll
    for (int m=0;m<HH;m++){
        float gm=g[m];
#pragma unroll
        for (int k=0;k<NO;k++) npj[k] += gm * w2[m*NO+k];
    }
#pragma unroll
    for (int k=0;k<NO;k++) npj[k]=elu_f(npj[k])*mk;

    float pav[HH], pbv[HH];
#pragma unroll
    for (int k=0;k<HH;k++){ pav[k]=pb0[k]; pbv[k]=0.0f; }
#pragma unroll
    for (int m=0;m<NO;m++){
        float nm=npj[m];
#pragma unroll
        for (int k=0;k<HH;k++){
            pav[k] += nm * pw0[m*HH+k];
            pbv[k] += nm * pw0[(NO+m)*HH+k];
        }
    }
    float4* pap = reinterpret_cast<float4*>(pa + (size_t)row*HH);
    float4* pbp = reinterpret_cast<float4*>(pb + (size_t)row*HH);
#pragma unroll
    for (int q=0;q<HH/4;q++){
        pap[q]=make_float4(pav[4*q],pav[4*q+1],pav[4*q+2],pav[4*q+3]);
        pbp[q]=make_float4(pbv[4*q],pbv[4*q+1],pbv[4*q+2],pbv[4*q+3]);
    }
}

// ---- Transposed-MFMA pair kernel, fp16, GRID-STRIDE WALKING WINDOW ----
// R15->R16: the write ADDRESS SCHEDULE, not the instruction pattern, is the
// suspect. All prior variants kept ~all blocks co-resident on disjoint slabs
// -> instantaneous store window spans the whole 128 MB output -> HBM row
// thrash (observed drain ~2.4 TB/s vs fills' 6.5 at compact sequential
// windows). Now: 1024 blocks (4/CU, ALL co-resident), block b handles output
// row s*1024+b at step s -> all blocks write a compact 16 MB window (2 MB
// per XCD L2) that walks forward, fill-style. Reads walk the same window.
// No LDS, no barriers: pa slice loaded per-lane from L2 (broadcast lines).
//   A frag (16x16x32): row m=ln(+16mt), k=8h+{0..7}
//   B frag: col=pair j=32w+16jj+ln, k=8h+{0..7}
//   D frag: col=pair j, feat 16mt+4h+{0..3} -> direct f32x4 stores
//   L1 D-frag == 16x16x16 B-frag (kc=mt chain) -> zero-LDS layer handoff.
__global__ __launch_bounds__(256, 4) void pair_kernel(
    const float* __restrict__ pa, const float* __restrict__ pb,
    const float* __restrict__ pw1, const float* __restrict__ pb1,
    const float* __restrict__ pw2, const float* __restrict__ pb2,
    float* __restrict__ out)
{
    const int t   = threadIdx.x;
    const int l   = t & 63;
    const int w   = t >> 6;
    const int h   = l >> 4;
    const int ln  = l & 15;
    const int b   = blockIdx.x;          // 0..1023

    // ---- Layer-1 W1^T A-fragments (16x16x32: k=8h+{0..7})
    f16x8 wfr1[2];   // [mt]
#pragma unroll
    for (int mt=0; mt<2; mt++){
        f16x8 a;
#pragma unroll
        for (int e=0; e<8; e++)
            a[e] = (_Float16)pw1[(8*h+e)*32 + 16*mt + ln];   // W1^T[m][k]=W1[k][m]
        wfr1[mt] = a;
    }
    // ---- Layer-2 W2^T A-fragments (16x16x16: k=4h+{0..3}, chained kc)
    f16x4 w2t[2][2]; // [mtO][kc]
#pragma unroll
    for (int mtO=0; mtO<2; mtO++)
#pragma unroll
    for (int kc=0; kc<2; kc++){
        f16x4 a;
#pragma unroll
        for (int e=0; e<4; e++)
            a[e] = (_Float16)pw2[(16*kc + 4*h + e)*32 + 16*mtO + ln];
        w2t[mtO][kc] = a;
    }

    // ---- biases as D-fragment f32x4 (feature = 16mt+4h+q)
    f32x4 b1v[2], b2v[2];
#pragma unroll
    for (int mt=0; mt<2; mt++){
        b1v[mt] = *(const f32x4*)(pb1 + 16*mt + 4*h);
        b2v[mt] = *(const f32x4*)(pb2 + 16*mt + 4*h);
    }

    for (int s = 0; s < 8; s++){
        const int row = s*1024 + b;        // walking window: rows [1024s,1024s+1024)
        const int bnb = row >> 7;

        // ---- pa slice for this row (L2 broadcast: 16 lanes share addr)
        float par[8];
        {
            const float* pp = pa + (size_t)row*HH + 8*h;
            f32x4 v0 = *(const f32x4*)pp, v1 = *(const f32x4*)(pp+4);
#pragma unroll
            for (int c=0;c<4;c++){ par[c]=v0[c]; par[4+c]=v1[c]; }
        }

        // ---- pb slices + H0^T B-fragments (fp16, packed cvt)
        f16x8 bh[2];
#pragma unroll
        for (int jj=0; jj<2; jj++){
            const float* q = pb + ((size_t)bnb*PP + 32*w + 16*jj + ln)*HH + 8*h;
            f32x4 v0 = *(const f32x4*)q, v1 = *(const f32x4*)(q+4);
            float e0[8];
#pragma unroll
            for (int c=0;c<4;c++){ e0[c]  = elu_f(par[c]   + v0[c]);
                                   e0[4+c]= elu_f(par[4+c] + v1[c]); }
            f16x2 p0 = pk16(e0[0], e0[1]);
            f16x2 p1 = pk16(e0[2], e0[3]);
            f16x2 p2 = pk16(e0[4], e0[5]);
            f16x2 p3 = pk16(e0[6], e0[7]);
            f16x8 bb = {p0[0],p0[1],p1[0],p1[1],p2[0],p2[1],p3[0],p3[1]};
            bh[jj] = bb;
        }

        // ---- Layer 1: H1^T = W1^T @ H0^T (K=32)
        f32x4 acc[2][2];   // [mt][jj]
#pragma unroll
        for (int mt=0; mt<2; mt++)
#pragma unroll
        for (int jj=0; jj<2; jj++)
            acc[mt][jj] = __builtin_amdgcn_mfma_f32_16x16x32_f16(
                              wfr1[mt], bh[jj], b1v[mt], 0,0,0);

        // ---- elu + cvt: acc IS the 16x16x16 B-fragment (kc = mt)
        f16x4 bf[2][2];    // [jj][kc]
#pragma unroll
        for (int jj=0; jj<2; jj++)
#pragma unroll
        for (int kc=0; kc<2; kc++){
            f16x2 q0 = pk16(elu_f(acc[kc][jj][0]), elu_f(acc[kc][jj][1]));
            f16x2 q1 = pk16(elu_f(acc[kc][jj][2]), elu_f(acc[kc][jj][3]));
            f16x4 pp = {q0[0],q0[1],q1[0],q1[1]};
            bf[jj][kc] = pp;
        }

        // ---- Layer 2: O^T = W2^T @ H1^T (2 chained K=16 MFMAs) + store
        float* obase = out + (size_t)row*PP*OUTC;
#pragma unroll
        for (int jj=0; jj<2; jj++){
            int j = 32*w + 16*jj + ln;
#pragma unroll
            for (int mtO=0; mtO<2; mtO++){
                f32x4 c = b2v[mtO];
                c = __builtin_amdgcn_mfma_f32_16x16x16f16(w2t[mtO][0], bf[jj][0], c, 0,0,0);
                c = __builtin_amdgcn_mfma_f32_16x16x16f16(w2t[mtO][1], bf[jj][1], c, 0,0,0);
                f32x4 o;
#pragma unroll
                for (int q=0; q<4; q++) o[q] = elu_f(c[q]);
                *(f32x4*)(obase + (size_t)j*OUTC + 16*mtO + 4*h) = o;
            }
        }
    }
}

extern "C" void kernel_launch(void* const* d_in, const int* in_sizes, int n_in,
                              void* d_out, int out_size, void* d_ws, size_t ws_size,
                              hipStream_t stream) {
    const float* x    = (const float*)d_in[0];
    const float* msk  = (const float*)d_in[1];
    const float* nw0  = (const float*)d_in[2];
    const float* nb0  = (const float*)d_in[3];
    const float* nw1  = (const float*)d_in[4];
    const float* nb1  = (const float*)d_in[5];
    const float* nw2  = (const float*)d_in[6];
    const float* nb2  = (const float*)d_in[7];
    const float* pw0  = (const float*)d_in[8];
    const float* pb0  = (const float*)d_in[9];
    const float* pw1  = (const float*)d_in[10];
    const float* pb1  = (const float*)d_in[11];
    const float* pw2  = (const float*)d_in[12];
    const float* pb2  = (const float*)d_in[13];
    float* out = (float*)d_out;

    float* pa = (float*)d_ws;                       // 8192*32 floats = 1 MiB
    float* pb = pa + (size_t)NROWS*HH;              // +1 MiB

    node_kernel<<<NROWS/256, 256, 0, stream>>>(x, msk, nw0, nb0, nw1, nb1,
                                               nw2, nb2, pw0, pb0, pa, pb);
    pair_kernel<<<1024, 256, 0, stream>>>(pa, pb, pw1, pb1,
                                          pw2, pb2, out);
}

// Round 17
// 66.308 us; speedup vs baseline: 1.1312x; 1.1312x over previous
//
#include <hip/hip_runtime.h>

// Problem dims (fixed by reference)
#define BB   2
#define NBB  32
#define PP   128
#define FF   32
#define HH   32
#define NO   8
#define OUTC 32
#define NROWS (BB*NBB*PP)   // 8192

typedef float    f32x4 __attribute__((ext_vector_type(4)));
typedef _Float16 f16x8 __attribute__((ext_vector_type(8)));
typedef _Float16 f16x4 __attribute__((ext_vector_type(4)));
typedef _Float16 f16x2 __attribute__((ext_vector_type(2)));

__device__ __forceinline__ float elu_f(float x){
    return x > 0.0f ? x : (__expf(x) - 1.0f);
}
// packed fp32x2 -> fp16x2 (RTZ), bit-cast to _Float16 vector type
__device__ __forceinline__ f16x2 pk16(float a, float b){
    return __builtin_bit_cast(f16x2, __builtin_amdgcn_cvt_pkrtz(a, b));
}

// Kernel A: node MLP + projection to pa/pb (pair_b0 folded into pa).
__global__ __launch_bounds__(256) void node_kernel(
    const float* __restrict__ x,  const float* __restrict__ msk,
    const float* __restrict__ w0, const float* __restrict__ b0,
    const float* __restrict__ w1, const float* __restrict__ b1,
    const float* __restrict__ w2, const float* __restrict__ b2,
    const float* __restrict__ pw0,const float* __restrict__ pb0,
    float* __restrict__ pa, float* __restrict__ pb)
{
    int row = blockIdx.x*256 + threadIdx.x;
    if (row >= NROWS) return;

    float xr[FF];
    const float4* xp = reinterpret_cast<const float4*>(x + (size_t)row*FF);
#pragma unroll
    for (int q=0;q<FF/4;q++){ float4 v=xp[q]; xr[4*q]=v.x; xr[4*q+1]=v.y; xr[4*q+2]=v.z; xr[4*q+3]=v.w; }

    float h[HH];
#pragma unroll
    for (int k=0;k<HH;k++) h[k]=b0[k];
#pragma unroll
    for (int m=0;m<FF;m++){
        float xm = xr[m];
#pragma unroll
        for (int k=0;k<HH;k++) h[k] += xm * w0[m*HH+k];
    }
#pragma unroll
    for (int k=0;k<HH;k++) h[k]=elu_f(h[k]);

    float g[HH];
#pragma unroll
    for (int k=0;k<HH;k++) g[k]=b1[k];
#pragma unroll
    for (int m=0;m<HH;m++){
        float hm=h[m];
#pragma unroll
        for (int k=0;k<HH;k++) g[k] += hm * w1[m*HH+k];
    }
#pragma unroll
    for (int k=0;k<HH;k++) g[k]=elu_f(g[k]);

    float mk = msk[row];
    float npj[NO];
#pragma unroll
    for (int k=0;k<NO;k++) npj[k]=b2[k];
#pragma unroll
    for (int m=0;m<HH;m++){
        float gm=g[m];
#pragma unroll
        for (int k=0;k<NO;k++) npj[k] += gm * w2[m*NO+k];
    }
#pragma unroll
    for (int k=0;k<NO;k++) npj[k]=elu_f(npj[k])*mk;

    float pav[HH], pbv[HH];
#pragma unroll
    for (int k=0;k<HH;k++){ pav[k]=pb0[k]; pbv[k]=0.0f; }
#pragma unroll
    for (int m=0;m<NO;m++){
        float nm=npj[m];
#pragma unroll
        for (int k=0;k<HH;k++){
            pav[k] += nm * pw0[m*HH+k];
            pbv[k] += nm * pw0[(NO+m)*HH+k];
        }
    }
    float4* pap = reinterpret_cast<float4*>(pa + (size_t)row*HH);
    float4* pbp = reinterpret_cast<float4*>(pb + (size_t)row*HH);
#pragma unroll
    for (int q=0;q<HH/4;q++){
        pap[q]=make_float4(pav[4*q],pav[4*q+1],pav[4*q+2],pav[4*q+3]);
        pbp[q]=make_float4(pbv[4*q],pbv[4*q+1],pbv[4*q+2],pbv[4*q+3]);
    }
}

// ---- Transposed-MFMA pair kernel, fp16, FORCED 2-DEEP STORE PIPELINE ----
// R16->R17: R13 body (2-jj, zero-LDS handoff, 1024 blocks) with ONE change:
// output fragments are double-buffered in registers with FORCED liveness.
// od[i&1] is filled at the end of iteration i but stored only at the TOP of
// iteration i+2 -- the values must survive through iteration i+1, so the
// allocator cannot recycle those VGPRs and the backend's s_waitcnt for
// store-data-register reuse gets >=2 iterations (~1400 cyc) of slack.
// Theory: all six prior structural edits nulled at ~66 us because each
// wave's stores serialized on register-reuse vmcnt waits (allocator reuses
// store-data regs for the next iteration's temporaries when minimizing
// VGPR), capping per-CU in-flight write traffic at ~1/3 of what the
// harness fill (32 light waves/CU, deep store queues) achieves.
//   A frag (16x16x32): row m=ln(+16mt), k=8h+{0..7}
//   B frag: col=pair j=32w+16jj+ln, k=8h+{0..7}
//   D frag: col=pair j, feat 16mt+4h+{0..3}
//   L1 D-frag == 16x16x16 B-frag (kc=mt chain) -> zero-LDS layer handoff.
#define SM_SIZE 1024     // pas: 8 rows * 32 f32

__global__ __launch_bounds__(256, 2) void pair_kernel(
    const float* __restrict__ pa, const float* __restrict__ pb,
    const float* __restrict__ pw1, const float* __restrict__ pb1,
    const float* __restrict__ pw2, const float* __restrict__ pb2,
    float* __restrict__ out)
{
    __shared__ __align__(16) float pas[SM_SIZE/4];

    const int t   = threadIdx.x;
    const int l   = t & 63;
    const int w   = t >> 6;
    const int h   = l >> 4;
    const int ln  = l & 15;
    const int bnb = blockIdx.x >> 4;
    const int ic  = blockIdx.x & 15;

    // ---- stage pa rows for this block's 8 i's (pair_b0 folded)
    if (t < 64)
        ((f32x4*)pas)[t] = ((const f32x4*)(pa + ((size_t)bnb*PP + ic*8)*HH))[t];

    // ---- Layer-1 W1^T A-fragments (16x16x32: k=8h+{0..7})
    f16x8 wfr1[2];   // [mt]
#pragma unroll
    for (int mt=0; mt<2; mt++){
        f16x8 a;
#pragma unroll
        for (int e=0; e<8; e++)
            a[e] = (_Float16)pw1[(8*h+e)*32 + 16*mt + ln];   // W1^T[m][k]=W1[k][m]
        wfr1[mt] = a;
    }
    // ---- Layer-2 W2^T A-fragments (16x16x16: k=4h+{0..3}, chained kc)
    f16x4 w2t[2][2]; // [mtO][kc]
#pragma unroll
    for (int mtO=0; mtO<2; mtO++)
#pragma unroll
    for (int kc=0; kc<2; kc++){
        f16x4 a;
#pragma unroll
        for (int e=0; e<4; e++)
            a[e] = (_Float16)pw2[(16*kc + 4*h + e)*32 + 16*mtO + ln];
        w2t[mtO][kc] = a;
    }

    // ---- biases as D-fragment f32x4 (feature = 16mt+4h+q)
    f32x4 b1v[2], b2v[2];
#pragma unroll
    for (int mt=0; mt<2; mt++){
        b1v[mt] = *(const f32x4*)(pb1 + 16*mt + 4*h);
        b2v[mt] = *(const f32x4*)(pb2 + 16*mt + 4*h);
    }

    // ---- pb slices (lane's B-frag k-slice for its 2 pair-tiles), hoisted
    float pbr[2][8];
#pragma unroll
    for (int jj=0; jj<2; jj++){
        const float* q = pb + ((size_t)bnb*PP + 32*w + 16*jj + ln)*HH + 8*h;
        f32x4 v0 = *(const f32x4*)q, v1 = *(const f32x4*)(q+4);
#pragma unroll
        for (int c=0;c<4;c++){ pbr[jj][c]=v0[c]; pbr[jj][4+c]=v1[c]; }
    }
    __syncthreads();   // pas visible to all

    // 2-deep store pipeline buffers: [parity][jj*2+mtO]
    f32x4 od[2][4];
    float* ob[2];

#pragma unroll
    for (int i = 0; i < 8; i++){
        // ---- drain the buffer we are about to refill (filled at i-2).
        // Forced liveness: od[i&1] survived all of iteration i-1.
        if (i >= 2){
            float* g0 = ob[i&1];
#pragma unroll
            for (int jj=0; jj<2; jj++){
                int j = 32*w + 16*jj + ln;
#pragma unroll
                for (int mtO=0; mtO<2; mtO++)
                    *(f32x4*)(g0 + (size_t)j*OUTC + 16*mtO + 4*h) = od[i&1][jj*2+mtO];
            }
        }

        // ---- H0^T B-fragments straight into registers (fp16, packed cvt)
        float par[8];
        {
            const f32x4* pp = (const f32x4*)(pas + i*32 + 8*h);
            f32x4 v0 = pp[0], v1 = pp[1];
#pragma unroll
            for (int c=0;c<4;c++){ par[c]=v0[c]; par[4+c]=v1[c]; }
        }
        f16x8 bh[2];
#pragma unroll
        for (int jj=0; jj<2; jj++){
            float e0[8];
#pragma unroll
            for (int e=0; e<8; e++) e0[e] = elu_f(par[e] + pbr[jj][e]);
            f16x2 p0 = pk16(e0[0], e0[1]);
            f16x2 p1 = pk16(e0[2], e0[3]);
            f16x2 p2 = pk16(e0[4], e0[5]);
            f16x2 p3 = pk16(e0[6], e0[7]);
            f16x8 b = {p0[0],p0[1],p1[0],p1[1],p2[0],p2[1],p3[0],p3[1]};
            bh[jj] = b;
        }

        // ---- Layer 1: H1^T = W1^T @ H0^T (K=32)
        f32x4 acc[2][2];   // [mt][jj]
#pragma unroll
        for (int mt=0; mt<2; mt++)
#pragma unroll
        for (int jj=0; jj<2; jj++)
            acc[mt][jj] = __builtin_amdgcn_mfma_f32_16x16x32_f16(
                              wfr1[mt], bh[jj], b1v[mt], 0,0,0);

        // ---- elu + cvt: acc IS the 16x16x16 B-fragment (kc = mt)
        f16x4 bf[2][2];    // [jj][kc]
#pragma unroll
        for (int jj=0; jj<2; jj++)
#pragma unroll
        for (int kc=0; kc<2; kc++){
            f16x2 q0 = pk16(elu_f(acc[kc][jj][0]), elu_f(acc[kc][jj][1]));
            f16x2 q1 = pk16(elu_f(acc[kc][jj][2]), elu_f(acc[kc][jj][3]));
            f16x4 pp = {q0[0],q0[1],q1[0],q1[1]};
            bf[jj][kc] = pp;
        }

        // ---- Layer 2: O^T = W2^T @ H1^T -> fill od[i&1] (stored at i+2)
#pragma unroll
        for (int jj=0; jj<2; jj++)
#pragma unroll
        for (int mtO=0; mtO<2; mtO++){
            f32x4 c = b2v[mtO];
            c = __builtin_amdgcn_mfma_f32_16x16x16f16(w2t[mtO][0], bf[jj][0], c, 0,0,0);
            c = __builtin_amdgcn_mfma_f32_16x16x16f16(w2t[mtO][1], bf[jj][1], c, 0,0,0);
            f32x4 o;
#pragma unroll
            for (int q=0; q<4; q++) o[q] = elu_f(c[q]);
            od[i&1][jj*2+mtO] = o;
        }
        ob[i&1] = out + ((size_t)(bnb*PP + ic*8 + i))*PP*OUTC;
    }

    // ---- epilogue: drain iterations 6 (od[0]) and 7 (od[1])
#pragma unroll
    for (int par2=0; par2<2; par2++){
        float* g0 = ob[par2];
#pragma unroll
        for (int jj=0; jj<2; jj++){
            int j = 32*w + 16*jj + ln;
#pragma unroll
            for (int mtO=0; mtO<2; mtO++)
                *(f32x4*)(g0 + (size_t)j*OUTC + 16*mtO + 4*h) = od[par2][jj*2+mtO];
        }
    }
}

extern "C" void kernel_launch(void* const* d_in, const int* in_sizes, int n_in,
                              void* d_out, int out_size, void* d_ws, size_t ws_size,
                              hipStream_t stream) {
    const float* x    = (const float*)d_in[0];
    const float* msk  = (const float*)d_in[1];
    const float* nw0  = (const float*)d_in[2];
    const float* nb0  = (const float*)d_in[3];
    const float* nw1  = (const float*)d_in[4];
    const float* nb1  = (const float*)d_in[5];
    const float* nw2  = (const float*)d_in[6];
    const float* nb2  = (const float*)d_in[7];
    const float* pw0  = (const float*)d_in[8];
    const float* pb0  = (const float*)d_in[9];
    const float* pw1  = (const float*)d_in[10];
    const float* pb1  = (const float*)d_in[11];
    const float* pw2  = (const float*)d_in[12];
    const float* pb2  = (const float*)d_in[13];
    float* out = (float*)d_out;

    float* pa = (float*)d_ws;                       // 8192*32 floats = 1 MiB
    float* pb = pa + (size_t)NROWS*HH;              // +1 MiB

    node_kernel<<<NROWS/256, 256, 0, stream>>>(x, msk, nw0, nb0, nw1, nb1,
                                               nw2, nb2, pw0, pb0, pa, pb);
    pair_kernel<<<BB*NBB*16, 256, 0, stream>>>(pa, pb, pw1, pb1,
                                               pw2, pb2, out);
}

// Round 18
// 54.108 us; speedup vs baseline: 1.3862x; 1.2255x over previous
//
#include <hip/hip_runtime.h>

// Problem dims (fixed by reference)
#define BB   2
#define NBB  32
#define PP   128
#define FF   32
#define HH   32
#define NO   8
#define OUTC 32
#define NROWS (BB*NBB*PP)   // 8192

typedef float    f32x4 __attribute__((ext_vector_type(4)));
typedef _Float16 f16x8 __attribute__((ext_vector_type(8)));
typedef _Float16 f16x4 __attribute__((ext_vector_type(4)));
typedef _Float16 f16x2 __attribute__((ext_vector_type(2)));

__device__ __forceinline__ float elu_f(float x){
    return x > 0.0f ? x : (__expf(x) - 1.0f);
}
// packed fp32x2 -> fp16x2 (RTZ), bit-cast to _Float16 vector type
__device__ __forceinline__ f16x2 pk16(float a, float b){
    return __builtin_bit_cast(f16x2, __builtin_amdgcn_cvt_pkrtz(a, b));
}

// Kernel A: node MLP + projection to pa/pb (pair_b0 folded into pa).
__global__ __launch_bounds__(256) void node_kernel(
    const float* __restrict__ x,  const float* __restrict__ msk,
    const float* __restrict__ w0, const float* __restrict__ b0,
    const float* __restrict__ w1, const float* __restrict__ b1,
    const float* __restrict__ w2, const float* __restrict__ b2,
    const float* __restrict__ pw0,const float* __restrict__ pb0,
    float* __restrict__ pa, float* __restrict__ pb)
{
    int row = blockIdx.x*256 + threadIdx.x;
    if (row >= NROWS) return;

    float xr[FF];
    const float4* xp = reinterpret_cast<const float4*>(x + (size_t)row*FF);
#pragma unroll
    for (int q=0;q<FF/4;q++){ float4 v=xp[q]; xr[4*q]=v.x; xr[4*q+1]=v.y; xr[4*q+2]=v.z; xr[4*q+3]=v.w; }

    float h[HH];
#pragma unroll
    for (int k=0;k<HH;k++) h[k]=b0[k];
#pragma unroll
    for (int m=0;m<FF;m++){
        float xm = xr[m];
#pragma unroll
        for (int k=0;k<HH;k++) h[k] += xm * w0[m*HH+k];
    }
#pragma unroll
    for (int k=0;k<HH;k++) h[k]=elu_f(h[k]);

    float g[HH];
#pragma unroll
    for (int k=0;k<HH;k++) g[k]=b1[k];
#pragma unroll
    for (int m=0;m<HH;m++){
        float hm=h[m];
#pragma unroll
        for (int k=0;k<HH;k++) g[k] += hm * w1[m*HH+k];
    }
#pragma unroll
    for (int k=0;k<HH;k++) g[k]=elu_f(g[k]);

    float mk = msk[row];
    float npj[NO];
#pragma unroll
    for (int k=0;k<NO;k++) npj[k]=b2[k];
#pragma unroll
    for (int m=0;m<HH;m++){
        float gm=g[m];
#pragma unroll
        for (int k=0;k<NO;k++) npj[k] += gm * w2[m*NO+k];
    }
#pragma unroll
    for (int k=0;k<NO;k++) npj[k]=elu_f(npj[k])*mk;

    float pav[HH], pbv[HH];
#pragma unroll
    for (int k=0;k<HH;k++){ pav[k]=pb0[k]; pbv[k]=0.0f; }
#pragma unroll
    for (int m=0;m<NO;m++){
        float nm=npj[m];
#pragma unroll
        for (int k=0;k<HH;k++){
            pav[k] += nm * pw0[m*HH+k];
            pbv[k] += nm * pw0[(NO+m)*HH+k];
        }
    }
    float4* pap = reinterpret_cast<float4*>(pa + (size_t)row*HH);
    float4* pbp = reinterpret_cast<float4*>(pb + (size_t)row*HH);
#pragma unroll
    for (int q=0;q<HH/4;q++){
        pap[q]=make_float4(pav[4*q],pav[4*q+1],pav[4*q+2],pav[4*q+3]);
        pbp[q]=make_float4(pbv[4*q],pbv[4*q+1],pbv[4*q+2],pbv[4*q+3]);
    }
}

// ---- Transposed-MFMA pair kernel, fp16, NT full-line streaming stores ----
// R17->R18 single change vs R15: the contiguous 1 KB writeout now uses
// __builtin_nontemporal_store. Each wave store-instruction covers a
// contiguous 1 KB span (8 full 128 B lines, 128 B-aligned base), so NT
// writes full sectors -- no RMW (R3's NT disaster was 16 B fragments at
// 128 B stride). Theory: our stores ALLOCATE dirty L2 lines that contend
// with the harness's 512 MiB inter-replay fill writeback, capping drain at
// ~2.3 TB/s vs the fill's 6.7; NT bypasses L2 allocation -> clean stream.
//   A frag (16x16x32): row m=ln(+16mt), k=8h+{0..7}
//   B frag: col=pair j, k=8h+{0..7};  D frag: col=pair j, feat 16mt+4h+{0..3}
//   L1 D-frag == 16x16x16 B-frag (kc=mt chain) -> zero-LDS layer handoff.
// Wave-local 2 KB LDS transpose tile (XOR-swizzled, no barriers).
#define SM_SIZE (1024 + 4*2048)   // pas + 4 wave tiles

__global__ __launch_bounds__(256, 5) void pair_kernel(
    const float* __restrict__ pa, const float* __restrict__ pb,
    const float* __restrict__ pw1, const float* __restrict__ pb1,
    const float* __restrict__ pw2, const float* __restrict__ pb2,
    float* __restrict__ out)
{
    __shared__ __align__(16) char smem[SM_SIZE];
    float* pas = (float*)smem;

    const int t   = threadIdx.x;
    const int l   = t & 63;
    const int w   = t >> 6;
    const int h   = l >> 4;
    const int ln  = l & 15;
    const int bnb = blockIdx.x >> 5;
    const int ic  = (blockIdx.x >> 1) & 15;
    const int p   = blockIdx.x & 1;
    const int jme = 64*p + 16*w + ln;      // this lane's pair row j
    char* tile = smem + 1024 + w*2048;     // wave-private transpose tile

    // ---- stage pa rows for this block's 8 i's (pair_b0 folded)
    if (t < 64)
        ((f32x4*)pas)[t] = ((const f32x4*)(pa + ((size_t)bnb*PP + ic*8)*HH))[t];

    // ---- Layer-1 W1^T A-fragments (16x16x32: k=8h+{0..7})
    f16x8 wfr1[2];   // [mt]
#pragma unroll
    for (int mt=0; mt<2; mt++){
        f16x8 a;
#pragma unroll
        for (int e=0; e<8; e++)
            a[e] = (_Float16)pw1[(8*h+e)*32 + 16*mt + ln];   // W1^T[m][k]=W1[k][m]
        wfr1[mt] = a;
    }
    // ---- Layer-2 W2^T A-fragments (16x16x16: k=4h+{0..3}, chained kc)
    f16x4 w2t[2][2]; // [mtO][kc]
#pragma unroll
    for (int mtO=0; mtO<2; mtO++)
#pragma unroll
    for (int kc=0; kc<2; kc++){
        f16x4 a;
#pragma unroll
        for (int e=0; e<4; e++)
            a[e] = (_Float16)pw2[(16*kc + 4*h + e)*32 + 16*mtO + ln];
        w2t[mtO][kc] = a;
    }

    // ---- biases as D-fragment f32x4 (feature = 16mt+4h+q)
    f32x4 b1v[2], b2v[2];
#pragma unroll
    for (int mt=0; mt<2; mt++){
        b1v[mt] = *(const f32x4*)(pb1 + 16*mt + 4*h);
        b2v[mt] = *(const f32x4*)(pb2 + 16*mt + 4*h);
    }

    // ---- pb slice: this lane's B-frag k-slice for its single j
    float pbr[8];
    {
        const float* q = pb + ((size_t)bnb*PP + jme)*HH + 8*h;
        f32x4 v0 = *(const f32x4*)q, v1 = *(const f32x4*)(q+4);
#pragma unroll
        for (int c=0;c<4;c++){ pbr[c]=v0[c]; pbr[4+c]=v1[c]; }
    }
    __syncthreads();   // pas visible to all

    for (int i = 0; i < 8; i++){
        // ---- H0^T B-fragment straight into registers (fp16, packed cvt)
        float par[8];
        {
            const f32x4* pp = (const f32x4*)(pas + i*32 + 8*h);
            f32x4 v0 = pp[0], v1 = pp[1];
#pragma unroll
            for (int c=0;c<4;c++){ par[c]=v0[c]; par[4+c]=v1[c]; }
        }
        float e0[8];
#pragma unroll
        for (int e=0; e<8; e++) e0[e] = elu_f(par[e] + pbr[e]);
        f16x2 p0 = pk16(e0[0], e0[1]);
        f16x2 p1 = pk16(e0[2], e0[3]);
        f16x2 p2 = pk16(e0[4], e0[5]);
        f16x2 p3 = pk16(e0[6], e0[7]);
        f16x8 bh = {p0[0],p0[1],p1[0],p1[1],p2[0],p2[1],p3[0],p3[1]};

        // ---- Layer 1: H1^T = W1^T @ H0^T (K=32)
        f32x4 acc[2];   // [mt]
#pragma unroll
        for (int mt=0; mt<2; mt++)
            acc[mt] = __builtin_amdgcn_mfma_f32_16x16x32_f16(
                          wfr1[mt], bh, b1v[mt], 0,0,0);

        // ---- elu + cvt: acc IS the 16x16x16 B-fragment (kc = mt)
        f16x4 bf[2];    // [kc]
#pragma unroll
        for (int kc=0; kc<2; kc++){
            f16x2 q0 = pk16(elu_f(acc[kc][0]), elu_f(acc[kc][1]));
            f16x2 q1 = pk16(elu_f(acc[kc][2]), elu_f(acc[kc][3]));
            f16x4 pp = {q0[0],q0[1],q1[0],q1[1]};
            bf[kc] = pp;
        }

        // ---- Layer 2: O^T = W2^T @ H1^T -> wave-local LDS tile (swizzled)
#pragma unroll
        for (int mtO=0; mtO<2; mtO++){
            f32x4 c = b2v[mtO];
            c = __builtin_amdgcn_mfma_f32_16x16x16f16(w2t[mtO][0], bf[0], c, 0,0,0);
            c = __builtin_amdgcn_mfma_f32_16x16x16f16(w2t[mtO][1], bf[1], c, 0,0,0);
            f32x4 o;
#pragma unroll
            for (int q=0; q<4; q++) o[q] = elu_f(c[q]);
            int slot = (4*mtO + h) ^ (ln & 7);
            *(f32x4*)(tile + ln*128 + slot*16) = o;
        }
        // wave-local RAW: lgkmcnt orders this wave's LDS writes before reads.

        // ---- contiguous NT writeout: 2 x 1 KB full-line streams per wave
        {
            float* gbase = out + ((size_t)(bnb*PP + ic*8 + i))*PP*OUTC
                               + (size_t)(64*p + 16*w)*OUTC;
#pragma unroll
            for (int r=0; r<2; r++){
                int L = l + 64*r;                 // 0..127 = 16 rows x 8 slots
                int j = L >> 3, s = (L & 7) ^ (j & 7);
                f32x4 v = *(const f32x4*)(tile + j*128 + s*16);
                __builtin_nontemporal_store(v, (f32x4*)(gbase + 4*L));
            }
        }
    }
}

extern "C" void kernel_launch(void* const* d_in, const int* in_sizes, int n_in,
                              void* d_out, int out_size, void* d_ws, size_t ws_size,
                              hipStream_t stream) {
    const float* x    = (const float*)d_in[0];
    const float* msk  = (const float*)d_in[1];
    const float* nw0  = (const float*)d_in[2];
    const float* nb0  = (const float*)d_in[3];
    const float* nw1  = (const float*)d_in[4];
    const float* nb1  = (const float*)d_in[5];
    const float* nw2  = (const float*)d_in[6];
    const float* nb2  = (const float*)d_in[7];
    const float* pw0  = (const float*)d_in[8];
    const float* pb0  = (const float*)d_in[9];
    const float* pw1  = (const float*)d_in[10];
    const float* pb1  = (const float*)d_in[11];
    const float* pw2  = (const float*)d_in[12];
    const float* pb2  = (const float*)d_in[13];
    float* out = (float*)d_out;

    float* pa = (float*)d_ws;                       // 8192*32 floats = 1 MiB
    float* pb = pa + (size_t)NROWS*HH;              // +1 MiB

    node_kernel<<<NROWS/256, 256, 0, stream>>>(x, msk, nw0, nb0, nw1, nb1,
                                               nw2, nb2, pw0, pb0, pa, pb);
    pair_kernel<<<BB*NBB*32, 256, 0, stream>>>(pa, pb, pw1, pb1,
                                               pw2, pb2, out);
}